// Round 4
// baseline (723.569 us; speedup 1.0000x reference)
//
#include <hip/hip_runtime.h>
#include <stdint.h>

#define NB   4096   // batch rows
#define LDIM 4096   // latent dim
#define KK   10     // k
#define TPB  256
#define CAP  1024   // survivor buffer entries (u64) -> 8 KB LDS

typedef float fx4 __attribute__((ext_vector_type(4)));  // native vec for nontemporal

__device__ __forceinline__ unsigned long long wave_min_u64(unsigned long long v) {
#pragma unroll
    for (int off = 1; off < 64; off <<= 1) {
        const unsigned long long o = __shfl_xor(v, off, 64);
        if (o < v) v = o;
    }
    return v;
}

__global__ __launch_bounds__(TPB) void topk_sparsemax(
    const float* __restrict__ logits,
    float* __restrict__ bv,      // [NB, KK, LDIM]
    float* __restrict__ distr,   // [NB, KK]
    float* __restrict__ entws,   // entmode==0: &ent (atomicAdd); ==1: ws[NB]
    const int entmode)
{
    __shared__ float s_wsum[4];
    __shared__ int   s_pos[KK];     // indices of k smallest |logit| (cost-ascending)
    __shared__ int   s_sign[KK];    // base bit at those positions (logit > 0)
    __shared__ int   s_bestm[KK];   // chosen flip-subset masks (cost ascending)
    __shared__ int   s_cnt;
    __shared__ unsigned long long s_cand[CAP];

    const int b    = blockIdx.x;
    const int t    = threadIdx.x;
    const int lane = t & 63;
    const int wv   = t >> 6;
    const float* __restrict__ row = logits + (size_t)b * LDIM;

    // ---- load 16 logits/thread, coalesced: element i -> col ((i>>2)<<10) + 4t + (i&3)
    float vals[16];
#pragma unroll
    for (int q = 0; q < 4; q++) {
        const float4 f = *(const float4*)(row + (q << 10) + (t << 2));
        vals[q*4+0] = f.x; vals[q*4+1] = f.y; vals[q*4+2] = f.z; vals[q*4+3] = f.w;
    }

    // ---- S0 = sum of positive logits (identical order to passing kernel)
    float s0 = 0.f;
#pragma unroll
    for (int i = 0; i < 16; i++) s0 += vals[i] > 0.f ? vals[i] : 0.f;
#pragma unroll
    for (int off = 1; off < 64; off <<= 1) s0 += __shfl_xor(s0, off, 64);
    if (lane == 0) s_wsum[wv] = s0;

    // ---- threshold compaction: survivors |v| < T into LDS (exact; retry + fallback)
    float T = 0.02f;   // ~65 expected survivors for N(0,1) x 4096
    int cnt = 0;
    for (int attempt = 0; attempt < 15; attempt++) {
        if (t == 0) s_cnt = 0;
        __syncthreads();
#pragma unroll
        for (int i = 0; i < 16; i++) {
            const float v    = vals[i];
            const float cost = fabsf(v);
            if (cost < T) {
                const int idx = ((i >> 2) << 10) + (t << 2) + (i & 3);
                const unsigned long long pk =
                    ((unsigned long long)__float_as_uint(cost) << 32)
                    | (unsigned)((idx << 1) | (v > 0.f ? 1 : 0));
                const int p = atomicAdd(&s_cnt, 1);
                if (p < CAP) s_cand[p] = pk;
            }
        }
        __syncthreads();
        cnt = s_cnt;                      // uniform across block
        if (cnt >= KK && cnt <= CAP) break;
        T = (cnt < KK) ? T * 4.0f : T * 0.25f;
        __syncthreads();                  // protect s_cnt reset on retry
    }

    // ---- wave 0 only: stage-1 select, subset sums, stage-2 select, sparsemax.
    if (wv == 0) {
        const float S0 = (s_wsum[0] + s_wsum[1]) + (s_wsum[2] + s_wsum[3]);
        float csm[KK];
        unsigned long long prev = 0ull;

        if (cnt >= KK && cnt <= CAP) {
            const int nc = cnt;
#pragma unroll
            for (int c = 0; c < KK; c++) {
                unsigned long long best = ~0ull;
                for (int p = lane; p < nc; p += 64) {
                    const unsigned long long pk = s_cand[p];
                    if ((c == 0 || pk > prev) && pk < best) best = pk;
                }
                best = wave_min_u64(best);
                prev = best;
                csm[c] = __uint_as_float((unsigned)(best >> 32));
                if (lane == 0) {
                    const unsigned lo = (unsigned)best;
                    s_pos[c]  = (int)(lo >> 1);
                    s_sign[c] = (int)(lo & 1u);
                }
            }
        } else {
            // exact fallback (pathological data only): wave0 rescans full row
#pragma unroll
            for (int c = 0; c < KK; c++) {
                unsigned long long best = ~0ull;
                for (int p = lane; p < LDIM; p += 64) {
                    const float v    = row[p];
                    const float cost = fabsf(v);
                    const unsigned long long pk =
                        ((unsigned long long)__float_as_uint(cost) << 32)
                        | (unsigned)((p << 1) | (v > 0.f ? 1 : 0));
                    if ((c == 0 || pk > prev) && pk < best) best = pk;
                }
                best = wave_min_u64(best);
                prev = best;
                csm[c] = __uint_as_float((unsigned)(best >> 32));
                if (lane == 0) {
                    const unsigned lo = (unsigned)best;
                    s_pos[c]  = (int)(lo >> 1);
                    s_sign[c] = (int)(lo & 1u);
                }
            }
        }

        // stage 2: 1024 subset sums, m = (lane<<4)|i, ascending-j accumulation
        float sums[16];
#pragma unroll
        for (int i = 0; i < 16; i++) {
            const int m = (lane << 4) | i;
            float acc = 0.f;
#pragma unroll
            for (int j = 0; j < KK; j++) acc += (m & (1 << j)) ? csm[j] : 0.f;
            sums[i] = acc;
        }

        float zc[KK];
        unsigned long long prev2 = 0ull;
#pragma unroll
        for (int c = 0; c < KK; c++) {
            unsigned long long best = ~0ull;
#pragma unroll
            for (int i = 0; i < 16; i++) {
                const unsigned long long pk =
                    ((unsigned long long)__float_as_uint(sums[i]) << 32)
                    | (unsigned)((lane << 4) | i);
                if ((c == 0 || pk > prev2) && pk < best) best = pk;
            }
            best = wave_min_u64(best);
            prev2 = best;
            zc[c] = S0 - __uint_as_float((unsigned)(best >> 32));
            if (lane == 0) s_bestm[c] = (int)((unsigned)best & 1023u);
        }

        // sparsemax + entropy (identical arithmetic to passing kernel)
        if (lane == 0) {
            float acc = 0.f; int ks = 0;
#pragma unroll
            for (int r = 1; r <= KK; r++) {
                acc += zc[r-1];
                if (1.f + (float)r * zc[r-1] > acc) ks++;
            }
            float acc2 = 0.f;
#pragma unroll
            for (int r = 0; r < KK; r++) if (r < ks) acc2 += zc[r];
            const float tau = (acc2 - 1.f) / (float)ks;
            float entl = 0.f;
            float* drow = distr + b * KK;
#pragma unroll
            for (int c = 0; c < KK; c++) {
                float p = zc[c] - tau;
                p = p > 0.f ? p : 0.f;
                drow[c] = p;
                if (p > 0.f) entl -= p * logf(p);
            }
            if (entmode) entws[b] = entl;
            else         atomicAdd(entws, entl * (1.0f / (float)NB));
        }
    }

    // ---- publish selection to all waves (only barrier between selection and stores)
    __syncthreads();

    // ---- per-thread flip info: for each of my 16 cols, a 10-bit row-flip mask
    //      + the flipped value. All indices compile-time (no scratch).
    unsigned fm[KK];     // fm[j] = mask over rows c of flip-bit j
#pragma unroll
    for (int j = 0; j < KK; j++) {
        unsigned m = 0u;
#pragma unroll
        for (int c = 0; c < KK; c++)
            m |= (((unsigned)s_bestm[c] >> j) & 1u) << c;
        fm[j] = m;
    }
    int posr[KK], sgnr[KK];
#pragma unroll
    for (int j = 0; j < KK; j++) { posr[j] = s_pos[j]; sgnr[j] = s_sign[j]; }

    unsigned rowflip[16]; float flipval[16]; float basef[16];
#pragma unroll
    for (int i = 0; i < 16; i++) {
        const int col = ((i >> 2) << 10) + (t << 2) + (i & 3);
        unsigned rf = 0u; float fv = 0.f;
#pragma unroll
        for (int j = 0; j < KK; j++) {
            if (posr[j] == col) { rf = fm[j]; fv = sgnr[j] ? 0.f : 1.f; }
        }
        rowflip[i] = rf; flipval[i] = fv;
        basef[i]   = vals[i] > 0.f ? 1.f : 0.f;
    }

    // ---- single-pass corrected bv write: each element written exactly once,
    //      non-temporal (bypass L2 for the 671 MB stream). No drain, no fixup.
    float* out0 = bv + (size_t)b * (KK * LDIM);
#pragma unroll
    for (int c = 0; c < KK; c++) {
        float* orow = out0 + c * LDIM + (t << 2);
#pragma unroll
        for (int q = 0; q < 4; q++) {
            fx4 v;
            v.x = ((rowflip[q*4+0] >> c) & 1u) ? flipval[q*4+0] : basef[q*4+0];
            v.y = ((rowflip[q*4+1] >> c) & 1u) ? flipval[q*4+1] : basef[q*4+1];
            v.z = ((rowflip[q*4+2] >> c) & 1u) ? flipval[q*4+2] : basef[q*4+2];
            v.w = ((rowflip[q*4+3] >> c) & 1u) ? flipval[q*4+3] : basef[q*4+3];
            __builtin_nontemporal_store(v, (fx4*)(orow + (q << 10)));
        }
    }
}

__global__ __launch_bounds__(256) void ent_reduce(
    const float* __restrict__ ws, float* __restrict__ ent)
{
    __shared__ float sw[4];
    const int t = threadIdx.x, lane = t & 63, wv = t >> 6;
    float s = 0.f;
    for (int i = t; i < NB; i += 256) s += ws[i];
#pragma unroll
    for (int off = 1; off < 64; off <<= 1) s += __shfl_xor(s, off, 64);
    if (lane == 0) sw[wv] = s;
    __syncthreads();
    if (t == 0) *ent = (sw[0] + sw[1] + sw[2] + sw[3]) * (1.0f / (float)NB);
}

extern "C" void kernel_launch(void* const* d_in, const int* in_sizes, int n_in,
                              void* d_out, int out_size, void* d_ws, size_t ws_size,
                              hipStream_t stream)
{
    const float* logits = (const float*)d_in[0];
    float* out   = (float*)d_out;
    float* bv    = out;
    float* distr = out + (size_t)NB * KK * LDIM;
    float* ent   = distr + (size_t)NB * KK;

    if (ws_size >= (size_t)NB * sizeof(float)) {
        // per-block entropy partials in workspace, reduced by a tiny second kernel
        topk_sparsemax<<<dim3(NB), dim3(TPB), 0, stream>>>(
            logits, bv, distr, (float*)d_ws, 1);
        ent_reduce<<<dim3(1), dim3(256), 0, stream>>>((const float*)d_ws, ent);
    } else {
        // fallback: accumulate into ent via device atomics
        (void)hipMemsetAsync(ent, 0, sizeof(float), stream);
        topk_sparsemax<<<dim3(NB), dim3(TPB), 0, stream>>>(
            logits, bv, distr, ent, 0);
    }
}

// Round 5
// 701.097 us; speedup vs baseline: 1.0321x; 1.0321x over previous
//
#include <hip/hip_runtime.h>
#include <stdint.h>

#define NB   4096   // batch rows
#define LDIM 4096   // latent dim
#define KK   10     // k
#define TPB  256
#define CAP  1024   // survivor buffer entries (u64) -> 8 KB LDS

typedef float fx4 __attribute__((ext_vector_type(4)));  // native vec for nontemporal

__device__ __forceinline__ unsigned long long wave_min_u64(unsigned long long v) {
#pragma unroll
    for (int off = 1; off < 64; off <<= 1) {
        const unsigned long long o = __shfl_xor(v, off, 64);
        if (o < v) v = o;
    }
    return v;
}

// ============================================================================
// Kernel 1: selection only. One block per row. Writes packed meta (10 u32),
// distr row, and entropy partial. No bv traffic.
// meta[s] = pos(12b) | fm<<12 (10b, mask over rows c with flip-bit s) | sign<<22
// ============================================================================
__global__ __launch_bounds__(TPB) void select_rows(
    const float* __restrict__ logits,
    float* __restrict__ distr,     // [NB, KK]
    float* __restrict__ entp,      // [NB] entropy partials
    unsigned* __restrict__ meta)   // [NB, KK]
{
    __shared__ float s_wsum[4];
    __shared__ int   s_pos[KK];
    __shared__ int   s_sign[KK];
    __shared__ int   s_bestm[KK];
    __shared__ int   s_cnt;
    __shared__ unsigned long long s_cand[CAP];

    const int b    = blockIdx.x;
    const int t    = threadIdx.x;
    const int lane = t & 63;
    const int wv   = t >> 6;
    const float* __restrict__ row = logits + (size_t)b * LDIM;

    // coalesced row load: element i -> col ((i>>2)<<10) + 4t + (i&3)
    float vals[16];
#pragma unroll
    for (int q = 0; q < 4; q++) {
        const float4 f = *(const float4*)(row + (q << 10) + (t << 2));
        vals[q*4+0] = f.x; vals[q*4+1] = f.y; vals[q*4+2] = f.z; vals[q*4+3] = f.w;
    }

    // S0 = sum of positive logits (identical reduction order to passing kernel)
    float s0 = 0.f;
#pragma unroll
    for (int i = 0; i < 16; i++) s0 += vals[i] > 0.f ? vals[i] : 0.f;
#pragma unroll
    for (int off = 1; off < 64; off <<= 1) s0 += __shfl_xor(s0, off, 64);
    if (lane == 0) s_wsum[wv] = s0;

    // threshold compaction (exact; retry + full-rescan fallback)
    float T = 0.02f;
    int cnt = 0;
    for (int attempt = 0; attempt < 15; attempt++) {
        if (t == 0) s_cnt = 0;
        __syncthreads();
#pragma unroll
        for (int i = 0; i < 16; i++) {
            const float v    = vals[i];
            const float cost = fabsf(v);
            if (cost < T) {
                const int idx = ((i >> 2) << 10) + (t << 2) + (i & 3);
                const unsigned long long pk =
                    ((unsigned long long)__float_as_uint(cost) << 32)
                    | (unsigned)((idx << 1) | (v > 0.f ? 1 : 0));
                const int p = atomicAdd(&s_cnt, 1);
                if (p < CAP) s_cand[p] = pk;
            }
        }
        __syncthreads();
        cnt = s_cnt;
        if (cnt >= KK && cnt <= CAP) break;
        T = (cnt < KK) ? T * 4.0f : T * 0.25f;
        __syncthreads();
    }

    if (wv != 0) return;   // no barriers below; waves 1-3 done

    const float S0 = (s_wsum[0] + s_wsum[1]) + (s_wsum[2] + s_wsum[3]);
    float csm[KK];
    unsigned long long prev = 0ull;

    if (cnt >= KK && cnt <= CAP) {
        const int nc = cnt;
#pragma unroll
        for (int c = 0; c < KK; c++) {
            unsigned long long best = ~0ull;
            for (int p = lane; p < nc; p += 64) {
                const unsigned long long pk = s_cand[p];
                if ((c == 0 || pk > prev) && pk < best) best = pk;
            }
            best = wave_min_u64(best);
            prev = best;
            csm[c] = __uint_as_float((unsigned)(best >> 32));
            if (lane == 0) {
                const unsigned lo = (unsigned)best;
                s_pos[c]  = (int)(lo >> 1);
                s_sign[c] = (int)(lo & 1u);
            }
        }
    } else {
        // exact fallback: wave0 rescans full row
#pragma unroll
        for (int c = 0; c < KK; c++) {
            unsigned long long best = ~0ull;
            for (int p = lane; p < LDIM; p += 64) {
                const float v    = row[p];
                const float cost = fabsf(v);
                const unsigned long long pk =
                    ((unsigned long long)__float_as_uint(cost) << 32)
                    | (unsigned)((p << 1) | (v > 0.f ? 1 : 0));
                if ((c == 0 || pk > prev) && pk < best) best = pk;
            }
            best = wave_min_u64(best);
            prev = best;
            csm[c] = __uint_as_float((unsigned)(best >> 32));
            if (lane == 0) {
                const unsigned lo = (unsigned)best;
                s_pos[c]  = (int)(lo >> 1);
                s_sign[c] = (int)(lo & 1u);
            }
        }
    }

    // stage 2: 1024 subset sums, m = (lane<<4)|i, ascending-j accumulation
    float sums[16];
#pragma unroll
    for (int i = 0; i < 16; i++) {
        const int m = (lane << 4) | i;
        float acc = 0.f;
#pragma unroll
        for (int j = 0; j < KK; j++) acc += (m & (1 << j)) ? csm[j] : 0.f;
        sums[i] = acc;
    }

    float zc[KK];
    unsigned long long prev2 = 0ull;
#pragma unroll
    for (int c = 0; c < KK; c++) {
        unsigned long long best = ~0ull;
#pragma unroll
        for (int i = 0; i < 16; i++) {
            const unsigned long long pk =
                ((unsigned long long)__float_as_uint(sums[i]) << 32)
                | (unsigned)((lane << 4) | i);
            if ((c == 0 || pk > prev2) && pk < best) best = pk;
        }
        best = wave_min_u64(best);
        prev2 = best;
        zc[c] = S0 - __uint_as_float((unsigned)(best >> 32));
        if (lane == 0) s_bestm[c] = (int)((unsigned)best & 1023u);
    }

    // sparsemax + entropy + meta (lane 0; identical arithmetic to passing kernel)
    if (lane == 0) {
        float acc = 0.f; int ks = 0;
#pragma unroll
        for (int r = 1; r <= KK; r++) {
            acc += zc[r-1];
            if (1.f + (float)r * zc[r-1] > acc) ks++;
        }
        float acc2 = 0.f;
#pragma unroll
        for (int r = 0; r < KK; r++) if (r < ks) acc2 += zc[r];
        const float tau = (acc2 - 1.f) / (float)ks;
        float entl = 0.f;
        float* drow = distr + b * KK;
#pragma unroll
        for (int c = 0; c < KK; c++) {
            float p = zc[c] - tau;
            p = p > 0.f ? p : 0.f;
            drow[c] = p;
            if (p > 0.f) entl -= p * logf(p);
        }
        entp[b] = entl;

        // packed meta: per slot s, mask over rows c whose subset flips bit s
        unsigned* mrow = meta + b * KK;
#pragma unroll
        for (int s = 0; s < KK; s++) {
            unsigned fm = 0u;
#pragma unroll
            for (int c = 0; c < KK; c++)
                fm |= (((unsigned)s_bestm[c] >> s) & 1u) << c;
            mrow[s] = (unsigned)s_pos[s] | (fm << 12) | ((unsigned)s_sign[s] << 22);
        }
    }
}

// ============================================================================
// Kernel 2: pure streaming writer, fill-like shape. 4 blocks per row, each
// covers 1024 cols x 10 rows. ~30 VGPRs, 40 B LDS -> high occupancy.
// ============================================================================
__global__ __launch_bounds__(TPB) void bv_writer(
    const float* __restrict__ logits,
    const unsigned* __restrict__ meta,
    float* __restrict__ bv)
{
    __shared__ unsigned s_m[KK];
    const int bid = blockIdx.x;
    const int b   = bid >> 2;
    const int seg = bid & 3;
    const int t   = threadIdx.x;
    if (t < KK) s_m[t] = meta[b * KK + t];
    __syncthreads();

    const int j0 = (seg << 10) + (t << 2);
    const float4 f = *(const float4*)(logits + (size_t)b * LDIM + j0);
    float basef[4];
    basef[0] = f.x > 0.f ? 1.f : 0.f;
    basef[1] = f.y > 0.f ? 1.f : 0.f;
    basef[2] = f.z > 0.f ? 1.f : 0.f;
    basef[3] = f.w > 0.f ? 1.f : 0.f;

    unsigned rf[4] = {0u, 0u, 0u, 0u};
    float    fv[4] = {0.f, 0.f, 0.f, 0.f};
#pragma unroll
    for (int s = 0; s < KK; s++) {
        const unsigned m   = s_m[s];
        const int      pos = (int)(m & 0xFFFu);
        const unsigned msk = (m >> 12) & 0x3FFu;
        const float    val = ((m >> 22) & 1u) ? 0.f : 1.f;
#pragma unroll
        for (int e = 0; e < 4; e++)
            if (pos == j0 + e) { rf[e] = msk; fv[e] = val; }
    }

    float* out0 = bv + (size_t)b * (KK * LDIM) + j0;
#pragma unroll
    for (int c = 0; c < KK; c++) {
        fx4 v;
        v.x = ((rf[0] >> c) & 1u) ? fv[0] : basef[0];
        v.y = ((rf[1] >> c) & 1u) ? fv[1] : basef[1];
        v.z = ((rf[2] >> c) & 1u) ? fv[2] : basef[2];
        v.w = ((rf[3] >> c) & 1u) ? fv[3] : basef[3];
        __builtin_nontemporal_store(v, (fx4*)(out0 + c * LDIM));
    }
}

__global__ __launch_bounds__(256) void ent_reduce(
    const float* __restrict__ ws, float* __restrict__ ent)
{
    __shared__ float sw[4];
    const int t = threadIdx.x, lane = t & 63, wv = t >> 6;
    float s = 0.f;
    for (int i = t; i < NB; i += 256) s += ws[i];
#pragma unroll
    for (int off = 1; off < 64; off <<= 1) s += __shfl_xor(s, off, 64);
    if (lane == 0) sw[wv] = s;
    __syncthreads();
    if (t == 0) *ent = (sw[0] + sw[1] + sw[2] + sw[3]) * (1.0f / (float)NB);
}

// ============================================================================
// Fallback fused kernel (round-4, verified passing) for tiny/absent workspace.
// ============================================================================
__global__ __launch_bounds__(TPB) void topk_sparsemax_fused(
    const float* __restrict__ logits,
    float* __restrict__ bv,
    float* __restrict__ distr,
    float* __restrict__ ent)
{
    __shared__ float s_wsum[4];
    __shared__ int   s_pos[KK];
    __shared__ int   s_sign[KK];
    __shared__ int   s_bestm[KK];
    __shared__ int   s_cnt;
    __shared__ unsigned long long s_cand[CAP];

    const int b    = blockIdx.x;
    const int t    = threadIdx.x;
    const int lane = t & 63;
    const int wv   = t >> 6;
    const float* __restrict__ row = logits + (size_t)b * LDIM;

    float vals[16];
#pragma unroll
    for (int q = 0; q < 4; q++) {
        const float4 f = *(const float4*)(row + (q << 10) + (t << 2));
        vals[q*4+0] = f.x; vals[q*4+1] = f.y; vals[q*4+2] = f.z; vals[q*4+3] = f.w;
    }

    float s0 = 0.f;
#pragma unroll
    for (int i = 0; i < 16; i++) s0 += vals[i] > 0.f ? vals[i] : 0.f;
#pragma unroll
    for (int off = 1; off < 64; off <<= 1) s0 += __shfl_xor(s0, off, 64);
    if (lane == 0) s_wsum[wv] = s0;

    float T = 0.02f;
    int cnt = 0;
    for (int attempt = 0; attempt < 15; attempt++) {
        if (t == 0) s_cnt = 0;
        __syncthreads();
#pragma unroll
        for (int i = 0; i < 16; i++) {
            const float v    = vals[i];
            const float cost = fabsf(v);
            if (cost < T) {
                const int idx = ((i >> 2) << 10) + (t << 2) + (i & 3);
                const unsigned long long pk =
                    ((unsigned long long)__float_as_uint(cost) << 32)
                    | (unsigned)((idx << 1) | (v > 0.f ? 1 : 0));
                const int p = atomicAdd(&s_cnt, 1);
                if (p < CAP) s_cand[p] = pk;
            }
        }
        __syncthreads();
        cnt = s_cnt;
        if (cnt >= KK && cnt <= CAP) break;
        T = (cnt < KK) ? T * 4.0f : T * 0.25f;
        __syncthreads();
    }

    if (wv == 0) {
        const float S0 = (s_wsum[0] + s_wsum[1]) + (s_wsum[2] + s_wsum[3]);
        float csm[KK];
        unsigned long long prev = 0ull;
        if (cnt >= KK && cnt <= CAP) {
            const int nc = cnt;
#pragma unroll
            for (int c = 0; c < KK; c++) {
                unsigned long long best = ~0ull;
                for (int p = lane; p < nc; p += 64) {
                    const unsigned long long pk = s_cand[p];
                    if ((c == 0 || pk > prev) && pk < best) best = pk;
                }
                best = wave_min_u64(best);
                prev = best;
                csm[c] = __uint_as_float((unsigned)(best >> 32));
                if (lane == 0) {
                    const unsigned lo = (unsigned)best;
                    s_pos[c]  = (int)(lo >> 1);
                    s_sign[c] = (int)(lo & 1u);
                }
            }
        } else {
#pragma unroll
            for (int c = 0; c < KK; c++) {
                unsigned long long best = ~0ull;
                for (int p = lane; p < LDIM; p += 64) {
                    const float v    = row[p];
                    const float cost = fabsf(v);
                    const unsigned long long pk =
                        ((unsigned long long)__float_as_uint(cost) << 32)
                        | (unsigned)((p << 1) | (v > 0.f ? 1 : 0));
                    if ((c == 0 || pk > prev) && pk < best) best = pk;
                }
                best = wave_min_u64(best);
                prev = best;
                csm[c] = __uint_as_float((unsigned)(best >> 32));
                if (lane == 0) {
                    const unsigned lo = (unsigned)best;
                    s_pos[c]  = (int)(lo >> 1);
                    s_sign[c] = (int)(lo & 1u);
                }
            }
        }
        float sums[16];
#pragma unroll
        for (int i = 0; i < 16; i++) {
            const int m = (lane << 4) | i;
            float acc = 0.f;
#pragma unroll
            for (int j = 0; j < KK; j++) acc += (m & (1 << j)) ? csm[j] : 0.f;
            sums[i] = acc;
        }
        float zc[KK];
        unsigned long long prev2 = 0ull;
#pragma unroll
        for (int c = 0; c < KK; c++) {
            unsigned long long best = ~0ull;
#pragma unroll
            for (int i = 0; i < 16; i++) {
                const unsigned long long pk =
                    ((unsigned long long)__float_as_uint(sums[i]) << 32)
                    | (unsigned)((lane << 4) | i);
                if ((c == 0 || pk > prev2) && pk < best) best = pk;
            }
            best = wave_min_u64(best);
            prev2 = best;
            zc[c] = S0 - __uint_as_float((unsigned)(best >> 32));
            if (lane == 0) s_bestm[c] = (int)((unsigned)best & 1023u);
        }
        if (lane == 0) {
            float acc = 0.f; int ks = 0;
#pragma unroll
            for (int r = 1; r <= KK; r++) {
                acc += zc[r-1];
                if (1.f + (float)r * zc[r-1] > acc) ks++;
            }
            float acc2 = 0.f;
#pragma unroll
            for (int r = 0; r < KK; r++) if (r < ks) acc2 += zc[r];
            const float tau = (acc2 - 1.f) / (float)ks;
            float entl = 0.f;
            float* drow = distr + b * KK;
#pragma unroll
            for (int c = 0; c < KK; c++) {
                float p = zc[c] - tau;
                p = p > 0.f ? p : 0.f;
                drow[c] = p;
                if (p > 0.f) entl -= p * logf(p);
            }
            atomicAdd(ent, entl * (1.0f / (float)NB));
        }
    }

    __syncthreads();

    unsigned fm[KK];
#pragma unroll
    for (int j = 0; j < KK; j++) {
        unsigned m = 0u;
#pragma unroll
        for (int c = 0; c < KK; c++)
            m |= (((unsigned)s_bestm[c] >> j) & 1u) << c;
        fm[j] = m;
    }
    int posr[KK], sgnr[KK];
#pragma unroll
    for (int j = 0; j < KK; j++) { posr[j] = s_pos[j]; sgnr[j] = s_sign[j]; }

    unsigned rowflip[16]; float flipval[16]; float basef[16];
#pragma unroll
    for (int i = 0; i < 16; i++) {
        const int col = ((i >> 2) << 10) + (t << 2) + (i & 3);
        unsigned rfm = 0u; float fvv = 0.f;
#pragma unroll
        for (int j = 0; j < KK; j++) {
            if (posr[j] == col) { rfm = fm[j]; fvv = sgnr[j] ? 0.f : 1.f; }
        }
        rowflip[i] = rfm; flipval[i] = fvv;
        basef[i]   = vals[i] > 0.f ? 1.f : 0.f;
    }

    float* out0 = bv + (size_t)b * (KK * LDIM);
#pragma unroll
    for (int c = 0; c < KK; c++) {
        float* orow = out0 + c * LDIM + (t << 2);
#pragma unroll
        for (int q = 0; q < 4; q++) {
            fx4 v;
            v.x = ((rowflip[q*4+0] >> c) & 1u) ? flipval[q*4+0] : basef[q*4+0];
            v.y = ((rowflip[q*4+1] >> c) & 1u) ? flipval[q*4+1] : basef[q*4+1];
            v.z = ((rowflip[q*4+2] >> c) & 1u) ? flipval[q*4+2] : basef[q*4+2];
            v.w = ((rowflip[q*4+3] >> c) & 1u) ? flipval[q*4+3] : basef[q*4+3];
            __builtin_nontemporal_store(v, (fx4*)(orow + (q << 10)));
        }
    }
}

extern "C" void kernel_launch(void* const* d_in, const int* in_sizes, int n_in,
                              void* d_out, int out_size, void* d_ws, size_t ws_size,
                              hipStream_t stream)
{
    const float* logits = (const float*)d_in[0];
    float* out   = (float*)d_out;
    float* bv    = out;
    float* distr = out + (size_t)NB * KK * LDIM;
    float* ent   = distr + (size_t)NB * KK;

    const size_t need = (size_t)NB * sizeof(float)            // entropy partials
                      + (size_t)NB * KK * sizeof(unsigned);   // packed meta
    if (ws_size >= need) {
        float*    entp = (float*)d_ws;
        unsigned* meta = (unsigned*)((float*)d_ws + NB);
        select_rows<<<dim3(NB), dim3(TPB), 0, stream>>>(logits, distr, entp, meta);
        bv_writer <<<dim3(NB * 4), dim3(TPB), 0, stream>>>(logits, meta, bv);
        ent_reduce<<<dim3(1), dim3(256), 0, stream>>>(entp, ent);
    } else {
        (void)hipMemsetAsync(ent, 0, sizeof(float), stream);
        topk_sparsemax_fused<<<dim3(NB), dim3(TPB), 0, stream>>>(logits, bv, distr, ent);
    }
}